// Round 15
// baseline (187.358 us; speedup 1.0000x reference)
//
#include <hip/hip_runtime.h>

#define DIMC   512
#define NHEADS 8
#define HDIM   64
#define DD     6
#define HHH    48
#define WWW    96
#define NPOS   (DD * HHH * WWW)   // 27648

typedef unsigned short u16;
typedef __attribute__((ext_vector_type(8))) short bf16x8;
typedef __attribute__((ext_vector_type(4))) float f32x4;

static __device__ __forceinline__ float b2f(u16 u) {
    return __builtin_bit_cast(float, (unsigned)u << 16);
}
static __device__ __forceinline__ u16 f2b(float f) {
    unsigned x = __builtin_bit_cast(unsigned, f);
    return (u16)((x + 0x7fffu + ((x >> 16) & 1u)) >> 16);
}

static __device__ __forceinline__ void gload_lds16(const void* g, void* l) {
    __builtin_amdgcn_global_load_lds((const __attribute__((address_space(1))) void*)g,
                                     (__attribute__((address_space(3))) void*)l, 16, 0, 0);
}

// ---------------------------------------------------------------------------
// converts (known-good)
// ---------------------------------------------------------------------------
__global__ __launch_bounds__(256) void cvt_x_bf16(const float* __restrict__ in,
                                                  u16* __restrict__ out, int n4) {
    const int i = blockIdx.x * 256 + threadIdx.x;
    float4 v = reinterpret_cast<const float4*>(in)[i];
    ushort4 o = { f2b(v.x), f2b(v.y), f2b(v.z), f2b(v.w) };
    reinterpret_cast<ushort4*>(out)[i] = o;
}

__global__ __launch_bounds__(256) void cvt_wqkvT(const float* __restrict__ w,
                                                 u16* __restrict__ o) {
    const int id = blockIdx.x * 256 + threadIdx.x;
    const int nn = id >> 9, kk = id & 511;
    o[id] = f2b(w[(size_t)kk * 1536 + nn]);
}

__global__ __launch_bounds__(256) void cvt_wprojT(const float* __restrict__ w,
                                                  u16* __restrict__ o) {
    const int id = blockIdx.x * 256 + threadIdx.x;   // 512*512 exact
    const int nn = id >> 9, kk = id & 511;
    o[id] = f2b(w[(size_t)kk * 512 + nn]);
}

// ---------------------------------------------------------------------------
// bf16 MFMA GEMM — R13 BK=64 configuration (known-good).
// ---------------------------------------------------------------------------
__global__ __launch_bounds__(256) void gemm_bf16_mfma(
    const u16* __restrict__ A, int lda,
    const u16* __restrict__ B, int ldb,
    const float* __restrict__ bias, int Kp,
    void* __restrict__ Cout, int ldc, int cmode, int nx)
{
    __shared__ u16 As[128 * 64];
    __shared__ u16 Bs[128 * 64];

    const int tid = threadIdx.x;
    const int l   = tid & 63;
    const int w   = tid >> 6;
    const int wr  = w >> 1, wc = w & 1;

    const int cpx = gridDim.x >> 3;
    const int idp = (blockIdx.x & 7) * cpx + (blockIdx.x >> 3);
    const int by  = idp / nx;
    const int bx  = idp - by * nx;
    const int m0  = by * 128;
    const int n0  = bx * 128;

    const int srow = tid >> 3;                        // 0..31
    const int schk = ((tid & 7) ^ (srow & 7)) * 8;    // source col elems (swz)

    const u16* ga = A + (size_t)(m0 + srow) * lda + schk;
    const u16* gb = B + (size_t)(n0 + srow) * ldb + schk;
    const size_t a32 = (size_t)32 * lda;
    const size_t b32 = (size_t)32 * ldb;
    u16* const la0 = As + (w * 8) * 64;
    u16* const lb0 = Bs + (w * 8) * 64;

    f32x4 acc[4][4];
#pragma unroll
    for (int i = 0; i < 4; i++)
#pragma unroll
        for (int j = 0; j < 4; j++) acc[i][j] = (f32x4)0.0f;

    const int c   = l & 15;
    const int g   = l >> 4;
    const int lk0 = (((0 * 4 + g) ^ (c & 7))) * 8;
    const int lk1 = (((1 * 4 + g) ^ (c & 7))) * 8;

#pragma unroll 1
    for (int k0 = 0; k0 < Kp; k0 += 64) {
#pragma unroll
        for (int q = 0; q < 4; ++q) {
            gload_lds16(ga + q * a32, la0 + q * 32 * 64);
            gload_lds16(gb + q * b32, lb0 + q * 32 * 64);
        }
        ga += 64; gb += 64;
        __syncthreads();

        {
            bf16x8 af[4], bfr[4];
#pragma unroll
            for (int f = 0; f < 4; f++) {
                af[f]  = *reinterpret_cast<const bf16x8*>(&As[(wr * 64 + f * 16 + c) * 64 + lk0]);
                bfr[f] = *reinterpret_cast<const bf16x8*>(&Bs[(wc * 64 + f * 16 + c) * 64 + lk0]);
            }
#pragma unroll
            for (int i = 0; i < 4; i++)
#pragma unroll
                for (int j = 0; j < 4; j++)
                    acc[i][j] = __builtin_amdgcn_mfma_f32_16x16x32_bf16(af[i], bfr[j], acc[i][j], 0, 0, 0);
        }
        {
            bf16x8 af[4], bfr[4];
#pragma unroll
            for (int f = 0; f < 4; f++) {
                af[f]  = *reinterpret_cast<const bf16x8*>(&As[(wr * 64 + f * 16 + c) * 64 + lk1]);
                bfr[f] = *reinterpret_cast<const bf16x8*>(&Bs[(wc * 64 + f * 16 + c) * 64 + lk1]);
            }
#pragma unroll
            for (int i = 0; i < 4; i++)
#pragma unroll
                for (int j = 0; j < 4; j++)
                    acc[i][j] = __builtin_amdgcn_mfma_f32_16x16x32_bf16(af[i], bfr[j], acc[i][j], 0, 0, 0);
        }
        __syncthreads();
    }

#pragma unroll
    for (int i = 0; i < 4; i++) {
        const int mb = m0 + wr * 64 + i * 16 + g * 4;
#pragma unroll
        for (int j = 0; j < 4; j++) {
            const int n = n0 + wc * 64 + j * 16 + c;
            const float bv = bias[n];
#pragma unroll
            for (int r = 0; r < 4; r++) {
                const float v = acc[i][j][r] + bv;
                if (cmode) reinterpret_cast<u16*>(Cout)[(size_t)(mb + r) * ldc + n] = f2b(v);
                else       reinterpret_cast<float*>(Cout)[(size_t)(mb + r) * ldc + n] = v;
            }
        }
    }
}

// ---------------------------------------------------------------------------
// MFMA neighborhood attention, 1x4x4 tiles — R15: R13 structure + wave-local
// register pipeline (T14). The s-loop has no barriers and Vt/Pbuf are
// wave-private (wave = head), so prefetch is race-free. K frags (4x bf16x8)
// and V octets (8x ushort4) for chunk s+1 are loaded into registers during
// chunk s; chunk s+1 starts by ds_writing the landed V regs (the compiler
// places the vmcnt wait there — gather latency hides under QK^T+PV of s).
// Explicit X/Y register double-buffer, loop unrolled x2 (all indices static).
// Arithmetic and op order identical to R13 -> bit-identical output.
// ---------------------------------------------------------------------------
__global__ __launch_bounds__(512, 4) void na3d_mfma(
    const u16* __restrict__ qkv, u16* __restrict__ attnc)
{
    __shared__ int   rowoff[192];
    __shared__ int   dlt[16];
    __shared__ u16   Pbuf[NHEADS][16][36];
    __shared__ u16   Vt[NHEADS][64][36];
    __shared__ float ssum_lds[NHEADS][16];

    const int bid  = blockIdx.x;
    const int tile = (bid & 7) * 216 + (bid >> 3);
    const int pd  = tile / 288;
    const int rem = tile - pd * 288;
    const int h0  = (rem / 24) * 4;
    const int w0  = (rem % 24) * 4;
    const int sd  = min(max(pd - 1, 0), DD - 3);
    const int shb = min(max(h0 - 2, 0), HHH - 5);
    const int swb = min(max(w0 - 2, 0), WWW - 5);

    const int tid = threadIdx.x;
    if (tid < 192) {
        const int dd = tid >> 6, hh = (tid >> 3) & 7, wu = tid & 7;
        const int row = (sd + dd) * (HHH * WWW)
                      + min(shb + hh, HHH - 1) * WWW + min(swb + wu, WWW - 1);
        rowoff[tid] = row * 1536;
    }
    if (tid < 16) {
        const int ph = h0 + (tid >> 2), pw = w0 + (tid & 3);
        const int dh = min(max(ph - 2, 0), HHH - 5) - shb;
        const int dw = min(max(pw - 2, 0), WWW - 5) - swb;
        dlt[tid] = (dh << 4) | dw;
    }
    __syncthreads();

    const int head  = tid >> 6;
    const int l     = tid & 63;
    const int g     = l >> 4;
    const int c     = l & 15;
    const int npair = l >> 2;
    const int chq   = l & 3;

    const int qrowi = pd * (HHH * WWW) + (h0 + (c >> 2)) * WWW + (w0 + (c & 3));
    const u16* qrow = qkv + (size_t)qrowi * 1536 + head * HDIM;
    const bf16x8 qlo = *reinterpret_cast<const bf16x8*>(qrow + 8 * g);
    const bf16x8 qhi = *reinterpret_cast<const bf16x8*>(qrow + 32 + 8 * g);
    const int dparts = dlt[c];
    const int dh = dparts >> 4, dw = dparts & 15;

    const u16* const vbase = qkv + 1024 + head * HDIM + 8 * chq;

    f32x4 oacc[4];
#pragma unroll
    for (int j = 0; j < 4; j++) oacc[j] = (f32x4)0.0f;
    float ssum = 0.0f;

    const float SC = 0.022542110f;   // log2(e)/64

#define LOADK_(sn, KL0, KH0, KL1, KH1) do {                                    \
    const int roA = rowoff[(sn) * 32 + c];                                     \
    const int roB = rowoff[(sn) * 32 + 16 + c];                                \
    const u16* krA = qkv + roA + 512 + head * HDIM;                            \
    const u16* krB = qkv + roB + 512 + head * HDIM;                            \
    KL0 = *reinterpret_cast<const bf16x8*>(krA + 8 * g);                       \
    KH0 = *reinterpret_cast<const bf16x8*>(krA + 32 + 8 * g);                  \
    KL1 = *reinterpret_cast<const bf16x8*>(krB + 8 * g);                       \
    KH1 = *reinterpret_cast<const bf16x8*>(krB + 32 + 8 * g);                  \
} while (0)

#define LOADV_(sn, V0, V1, V2, V3, V4, V5, V6, V7) do {                        \
    const int2 rp = *reinterpret_cast<const int2*>(&rowoff[(sn) * 32 + 2 * npair]); \
    const ushort4* pa = reinterpret_cast<const ushort4*>(vbase + rp.x);        \
    const ushort4* pb = reinterpret_cast<const ushort4*>(vbase + rp.y);        \
    V0 = pa[0]; V1 = pa[1]; V2 = pb[0]; V3 = pb[1];                            \
    V4 = pa[8]; V5 = pa[9]; V6 = pb[8]; V7 = pb[9];                            \
} while (0)

#define PACK4_(rowbase, VA, VB) do {                                           \
    const u16* _a = reinterpret_cast<const u16*>(&(VA));                       \
    const u16* _b = reinterpret_cast<const u16*>(&(VB));                       \
    *reinterpret_cast<unsigned*>(&Vt[head][(rowbase) + 0][2 * npair]) = (unsigned)_a[0] | ((unsigned)_b[0] << 16); \
    *reinterpret_cast<unsigned*>(&Vt[head][(rowbase) + 1][2 * npair]) = (unsigned)_a[1] | ((unsigned)_b[1] << 16); \
    *reinterpret_cast<unsigned*>(&Vt[head][(rowbase) + 2][2 * npair]) = (unsigned)_a[2] | ((unsigned)_b[2] << 16); \
    *reinterpret_cast<unsigned*>(&Vt[head][(rowbase) + 3][2 * npair]) = (unsigned)_a[3] | ((unsigned)_b[3] << 16); \
} while (0)

#define WRITEV_(V0, V1, V2, V3, V4, V5, V6, V7) do {                           \
    PACK4_(8 * chq,      V0, V2);                                              \
    PACK4_(8 * chq + 4,  V1, V3);                                              \
    PACK4_(8 * chq + 32, V4, V6);                                              \
    PACK4_(8 * chq + 36, V5, V7);                                              \
} while (0)

#define QKT_(s, t, KLO, KHI) do {                                              \
    f32x4 sf = (f32x4)0.0f;                                                    \
    sf = __builtin_amdgcn_mfma_f32_16x16x32_bf16(KLO, qlo, sf, 0, 0, 0);       \
    sf = __builtin_amdgcn_mfma_f32_16x16x32_bf16(KHI, qhi, sf, 0, 0, 0);       \
    const int sb  = (s) * 32 + (t) * 16 + 4 * g;                               \
    const int wu0 = sb & 7;                                                    \
    const int hh_ = (sb >> 3) & 7;                                             \
    const bool hv = ((unsigned)(hh_ - dh) < 5u);                               \
    const float e0 = (hv && (unsigned)(wu0 + 0 - dw) < 5u) ? exp2f(sf[0] * SC) : 0.0f; \
    const float e1 = (hv && (unsigned)(wu0 + 1 - dw) < 5u) ? exp2f(sf[1] * SC) : 0.0f; \
    const float e2 = (hv && (unsigned)(wu0 + 2 - dw) < 5u) ? exp2f(sf[2] * SC) : 0.0f; \
    const float e3 = (hv && (unsigned)(wu0 + 3 - dw) < 5u) ? exp2f(sf[3] * SC) : 0.0f; \
    ssum += e0 + e1 + e2 + e3;                                                 \
    const unsigned p01 = (unsigned)f2b(e0) | ((unsigned)f2b(e1) << 16);        \
    const unsigned p23 = (unsigned)f2b(e2) | ((unsigned)f2b(e3) << 16);        \
    *reinterpret_cast<unsigned*>(&Pbuf[head][c][(t) * 16 + 4 * g])     = p01;  \
    *reinterpret_cast<unsigned*>(&Pbuf[head][c][(t) * 16 + 4 * g + 2]) = p23;  \
} while (0)

#define PV_() do {                                                             \
    const uint2 p01 = *reinterpret_cast<const uint2*>(&Pbuf[head][c][8 * g]);  \
    const uint2 p23 = *reinterpret_cast<const uint2*>(&Pbuf[head][c][8 * g + 4]); \
    const int4 pv = make_int4((int)p01.x, (int)p01.y, (int)p23.x, (int)p23.y); \
    const bf16x8 pfrag = __builtin_bit_cast(bf16x8, pv);                       \
    const uint2 v01a = *reinterpret_cast<const uint2*>(&Vt[head][c][8 * g]);   \
    const uint2 v23a = *reinterpret_cast<const uint2*>(&Vt[head][c][8 * g + 4]); \
    oacc[0] = __builtin_amdgcn_mfma_f32_16x16x32_bf16(pfrag, __builtin_bit_cast(bf16x8, make_int4((int)v01a.x, (int)v01a.y, (int)v23a.x, (int)v23a.y)), oacc[0], 0, 0, 0); \
    const uint2 v01b = *reinterpret_cast<const uint2*>(&Vt[head][16 + c][8 * g]); \
    const uint2 v23b = *reinterpret_cast<const uint2*>(&Vt[head][16 + c][8 * g + 4]); \
    oacc[1] = __builtin_amdgcn_mfma_f32_16x16x32_bf16(pfrag, __builtin_bit_cast(bf16x8, make_int4((int)v01b.x, (int)v01b.y, (int)v23b.x, (int)v23b.y)), oacc[1], 0, 0, 0); \
    const uint2 v01c = *reinterpret_cast<const uint2*>(&Vt[head][32 + c][8 * g]); \
    const uint2 v23c = *reinterpret_cast<const uint2*>(&Vt[head][32 + c][8 * g + 4]); \
    oacc[2] = __builtin_amdgcn_mfma_f32_16x16x32_bf16(pfrag, __builtin_bit_cast(bf16x8, make_int4((int)v01c.x, (int)v01c.y, (int)v23c.x, (int)v23c.y)), oacc[2], 0, 0, 0); \
    const uint2 v01d = *reinterpret_cast<const uint2*>(&Vt[head][48 + c][8 * g]); \
    const uint2 v23d = *reinterpret_cast<const uint2*>(&Vt[head][48 + c][8 * g + 4]); \
    oacc[3] = __builtin_amdgcn_mfma_f32_16x16x32_bf16(pfrag, __builtin_bit_cast(bf16x8, make_int4((int)v01d.x, (int)v01d.y, (int)v23d.x, (int)v23d.y)), oacc[3], 0, 0, 0); \
} while (0)

    bf16x8 xk0, xk1, xk2, xk3, yk0, yk1, yk2, yk3;
    ushort4 xv0, xv1, xv2, xv3, xv4, xv5, xv6, xv7;
    ushort4 yv0, yv1, yv2, yv3, yv4, yv5, yv6, yv7;

    LOADK_(0, xk0, xk1, xk2, xk3);
    LOADV_(0, xv0, xv1, xv2, xv3, xv4, xv5, xv6, xv7);

#pragma unroll 1
    for (int i = 0; i < 3; ++i) {
        const int s0 = 2 * i, s1 = 2 * i + 1;
        const int s2 = (s1 < 5) ? s1 + 1 : 5;

        // chunk s0: consume X, prefetch Y(s1)
        WRITEV_(xv0, xv1, xv2, xv3, xv4, xv5, xv6, xv7);
        LOADV_(s1, yv0, yv1, yv2, yv3, yv4, yv5, yv6, yv7);
        LOADK_(s1, yk0, yk1, yk2, yk3);
        QKT_(s0, 0, xk0, xk1);
        QKT_(s0, 1, xk2, xk3);
        PV_();

        // chunk s1: consume Y, prefetch X(s2)
        WRITEV_(yv0, yv1, yv2, yv3, yv4, yv5, yv6, yv7);
        LOADV_(s2, xv0, xv1, xv2, xv3, xv4, xv5, xv6, xv7);
        LOADK_(s2, xk0, xk1, xk2, xk3);
        QKT_(s1, 0, yk0, yk1);
        QKT_(s1, 1, yk2, yk3);
        PV_();
    }

#undef LOADK_
#undef LOADV_
#undef PACK4_
#undef WRITEV_
#undef QKT_
#undef PV_

    ssum += __shfl_xor(ssum, 16);
    ssum += __shfl_xor(ssum, 32);
    if (l < 16) ssum_lds[head][c] = ssum;
    const f32x4 sums4 = *reinterpret_cast<const f32x4*>(&ssum_lds[head][4 * g]);

    const int orow = pd * (HHH * WWW) + (h0 + g) * WWW + w0;
#pragma unroll
    for (int r = 0; r < 4; ++r) {
        const float inv = 1.0f / sums4[r];
        u16* base = attnc + (size_t)(orow + r) * 512 + head * HDIM;
#pragma unroll
        for (int j = 0; j < 4; ++j)
            base[16 * j + c] = f2b(oacc[j][r] * inv);
    }
}

// ---------------------------------------------------------------------------
extern "C" void kernel_launch(void* const* d_in, const int* in_sizes, int n_in,
                              void* d_out, int out_size, void* d_ws, size_t ws_size,
                              hipStream_t stream)
{
    const float* x      = (const float*)d_in[0];
    const float* w_qkv  = (const float*)d_in[1];
    const float* b_qkv  = (const float*)d_in[2];
    const float* w_proj = (const float*)d_in[3];
    const float* b_proj = (const float*)d_in[4];
    float* out = (float*)d_out;

    u16* qkvb   = (u16*)d_ws;                         // [27648][1536]
    u16* attnc  = qkvb  + (size_t)NPOS * 1536;        // [27648][512] bf16
    u16* xb     = attnc + (size_t)NPOS * 512;         // [27648][512]
    u16* wqkvT  = xb    + (size_t)NPOS * 512;         // [1536][512]
    u16* wprojT = wqkvT + (size_t)1536 * 512;         // [512][512]

    cvt_x_bf16<<<(NPOS * 512 / 4) / 256, 256, 0, stream>>>(x, xb, NPOS * 512 / 4);
    cvt_wqkvT<<<(1536 * 512) / 256, 256, 0, stream>>>(w_qkv, wqkvT);
    cvt_wprojT<<<(512 * 512) / 256, 256, 0, stream>>>(w_proj, wprojT);

    // 1) qkv = x @ w_qkv + b_qkv  (bf16, K=512); grid 2592 = 8*324, nx=12
    gemm_bf16_mfma<<<(1536 / 128) * (NPOS / 128), 256, 0, stream>>>(
        xb, 512, wqkvT, 512, b_qkv, 512, qkvb, 1536, 1, 1536 / 128);

    // 2) attention -> bf16 [NPOS][512]
    na3d_mfma<<<NPOS / 16, 512, 0, stream>>>(qkvb, attnc);

    // 3) out = attn @ w_proj + b_proj  (bf16, K=512); grid 864 = 8*108, nx=4
    gemm_bf16_mfma<<<(512 / 128) * (NPOS / 128), 256, 0, stream>>>(
        attnc, 512, wprojT, 512, b_proj, 512, out, 512, 0, 512 / 128);
}

// Round 16
// 180.036 us; speedup vs baseline: 1.0407x; 1.0407x over previous
//
#include <hip/hip_runtime.h>

#define DIMC   512
#define NHEADS 8
#define HDIM   64
#define DD     6
#define HHH    48
#define WWW    96
#define NPOS   (DD * HHH * WWW)   // 27648

typedef unsigned short u16;
typedef __attribute__((ext_vector_type(8))) short bf16x8;
typedef __attribute__((ext_vector_type(4))) float f32x4;

static __device__ __forceinline__ float b2f(u16 u) {
    return __builtin_bit_cast(float, (unsigned)u << 16);
}
static __device__ __forceinline__ u16 f2b(float f) {
    unsigned x = __builtin_bit_cast(unsigned, f);
    return (u16)((x + 0x7fffu + ((x >> 16) & 1u)) >> 16);
}

static __device__ __forceinline__ void gload_lds16(const void* g, void* l) {
    __builtin_amdgcn_global_load_lds((const __attribute__((address_space(1))) void*)g,
                                     (__attribute__((address_space(3))) void*)l, 16, 0, 0);
}

// ---------------------------------------------------------------------------
// converts (known-good)
// ---------------------------------------------------------------------------
__global__ __launch_bounds__(256) void cvt_x_bf16(const float* __restrict__ in,
                                                  u16* __restrict__ out, int n4) {
    const int i = blockIdx.x * 256 + threadIdx.x;
    float4 v = reinterpret_cast<const float4*>(in)[i];
    ushort4 o = { f2b(v.x), f2b(v.y), f2b(v.z), f2b(v.w) };
    reinterpret_cast<ushort4*>(out)[i] = o;
}

__global__ __launch_bounds__(256) void cvt_wqkvT(const float* __restrict__ w,
                                                 u16* __restrict__ o) {
    const int id = blockIdx.x * 256 + threadIdx.x;
    const int nn = id >> 9, kk = id & 511;
    o[id] = f2b(w[(size_t)kk * 1536 + nn]);
}

__global__ __launch_bounds__(256) void cvt_wprojT(const float* __restrict__ w,
                                                  u16* __restrict__ o) {
    const int id = blockIdx.x * 256 + threadIdx.x;   // 512*512 exact
    const int nn = id >> 9, kk = id & 511;
    o[id] = f2b(w[(size_t)kk * 512 + nn]);
}

// ---------------------------------------------------------------------------
// bf16 MFMA GEMM — R13 BK=64 configuration (known-good).
// ---------------------------------------------------------------------------
__global__ __launch_bounds__(256) void gemm_bf16_mfma(
    const u16* __restrict__ A, int lda,
    const u16* __restrict__ B, int ldb,
    const float* __restrict__ bias, int Kp,
    void* __restrict__ Cout, int ldc, int cmode, int nx)
{
    __shared__ u16 As[128 * 64];
    __shared__ u16 Bs[128 * 64];

    const int tid = threadIdx.x;
    const int l   = tid & 63;
    const int w   = tid >> 6;
    const int wr  = w >> 1, wc = w & 1;

    const int cpx = gridDim.x >> 3;
    const int idp = (blockIdx.x & 7) * cpx + (blockIdx.x >> 3);
    const int by  = idp / nx;
    const int bx  = idp - by * nx;
    const int m0  = by * 128;
    const int n0  = bx * 128;

    const int srow = tid >> 3;                        // 0..31
    const int schk = ((tid & 7) ^ (srow & 7)) * 8;    // source col elems (swz)

    const u16* ga = A + (size_t)(m0 + srow) * lda + schk;
    const u16* gb = B + (size_t)(n0 + srow) * ldb + schk;
    const size_t a32 = (size_t)32 * lda;
    const size_t b32 = (size_t)32 * ldb;
    u16* const la0 = As + (w * 8) * 64;
    u16* const lb0 = Bs + (w * 8) * 64;

    f32x4 acc[4][4];
#pragma unroll
    for (int i = 0; i < 4; i++)
#pragma unroll
        for (int j = 0; j < 4; j++) acc[i][j] = (f32x4)0.0f;

    const int c   = l & 15;
    const int g   = l >> 4;
    const int lk0 = (((0 * 4 + g) ^ (c & 7))) * 8;
    const int lk1 = (((1 * 4 + g) ^ (c & 7))) * 8;

#pragma unroll 1
    for (int k0 = 0; k0 < Kp; k0 += 64) {
#pragma unroll
        for (int q = 0; q < 4; ++q) {
            gload_lds16(ga + q * a32, la0 + q * 32 * 64);
            gload_lds16(gb + q * b32, lb0 + q * 32 * 64);
        }
        ga += 64; gb += 64;
        __syncthreads();

        {
            bf16x8 af[4], bfr[4];
#pragma unroll
            for (int f = 0; f < 4; f++) {
                af[f]  = *reinterpret_cast<const bf16x8*>(&As[(wr * 64 + f * 16 + c) * 64 + lk0]);
                bfr[f] = *reinterpret_cast<const bf16x8*>(&Bs[(wc * 64 + f * 16 + c) * 64 + lk0]);
            }
#pragma unroll
            for (int i = 0; i < 4; i++)
#pragma unroll
                for (int j = 0; j < 4; j++)
                    acc[i][j] = __builtin_amdgcn_mfma_f32_16x16x32_bf16(af[i], bfr[j], acc[i][j], 0, 0, 0);
        }
        {
            bf16x8 af[4], bfr[4];
#pragma unroll
            for (int f = 0; f < 4; f++) {
                af[f]  = *reinterpret_cast<const bf16x8*>(&As[(wr * 64 + f * 16 + c) * 64 + lk1]);
                bfr[f] = *reinterpret_cast<const bf16x8*>(&Bs[(wc * 64 + f * 16 + c) * 64 + lk1]);
            }
#pragma unroll
            for (int i = 0; i < 4; i++)
#pragma unroll
                for (int j = 0; j < 4; j++)
                    acc[i][j] = __builtin_amdgcn_mfma_f32_16x16x32_bf16(af[i], bfr[j], acc[i][j], 0, 0, 0);
        }
        __syncthreads();
    }

#pragma unroll
    for (int i = 0; i < 4; i++) {
        const int mb = m0 + wr * 64 + i * 16 + g * 4;
#pragma unroll
        for (int j = 0; j < 4; j++) {
            const int n = n0 + wc * 64 + j * 16 + c;
            const float bv = bias[n];
#pragma unroll
            for (int r = 0; r < 4; r++) {
                const float v = acc[i][j][r] + bv;
                if (cmode) reinterpret_cast<u16*>(Cout)[(size_t)(mb + r) * ldc + n] = f2b(v);
                else       reinterpret_cast<float*>(Cout)[(size_t)(mb + r) * ldc + n] = v;
            }
        }
    }
}

// ---------------------------------------------------------------------------
// MFMA neighborhood attention, 1x4x4 tiles — R16: Pbuf eliminated via
// permlane register transpose. QK^T leaves P packed in 4 dwords/lane
// (pA=p01_t0, pB=p23_t0, pC=p01_t1, pD=p23_t1; lane (g,c) holds slot-pair
// dwords d(2g),d(2g+1) / d(8+2g),d(9+2g)). PV needs d(4g)..d(4g+3).
// permlane32_swap then permlane16_swap on (pA,pC) yields pf0=[d0,d4,d8,d12],
// pf2=[d2,d6,d10,d14]; same on (pB,pD) -> pf1, pf3. 4 VALU ops replace
// 4 ds_write + 2 ds_read + two dependent LDS latencies per chunk; Pbuf LDS
// freed (47.6 -> 37.3 KB, 4 blocks/CU). Same e-values, same MFMA order ->
// bit-identical output. Body otherwise = R13 (R15's neutral pipeline dropped).
// ---------------------------------------------------------------------------
__global__ __launch_bounds__(512, 4) void na3d_mfma(
    const u16* __restrict__ qkv, u16* __restrict__ attnc)
{
    __shared__ int   rowoff[192];
    __shared__ int   dlt[16];
    __shared__ u16   Vt[NHEADS][64][36];
    __shared__ float ssum_lds[NHEADS][16];

    const int bid  = blockIdx.x;
    const int tile = (bid & 7) * 216 + (bid >> 3);
    const int pd  = tile / 288;
    const int rem = tile - pd * 288;
    const int h0  = (rem / 24) * 4;
    const int w0  = (rem % 24) * 4;
    const int sd  = min(max(pd - 1, 0), DD - 3);
    const int shb = min(max(h0 - 2, 0), HHH - 5);
    const int swb = min(max(w0 - 2, 0), WWW - 5);

    const int tid = threadIdx.x;
    if (tid < 192) {
        const int dd = tid >> 6, hh = (tid >> 3) & 7, wu = tid & 7;
        const int row = (sd + dd) * (HHH * WWW)
                      + min(shb + hh, HHH - 1) * WWW + min(swb + wu, WWW - 1);
        rowoff[tid] = row * 1536;
    }
    if (tid < 16) {
        const int ph = h0 + (tid >> 2), pw = w0 + (tid & 3);
        const int dh = min(max(ph - 2, 0), HHH - 5) - shb;
        const int dw = min(max(pw - 2, 0), WWW - 5) - swb;
        dlt[tid] = (dh << 4) | dw;
    }
    __syncthreads();

    const int head = tid >> 6;
    const int l    = tid & 63;
    const int g    = l >> 4;
    const int c    = l & 15;

    const int qrowi = pd * (HHH * WWW) + (h0 + (c >> 2)) * WWW + (w0 + (c & 3));
    const u16* qrow = qkv + (size_t)qrowi * 1536 + head * HDIM;
    const bf16x8 qlo = *reinterpret_cast<const bf16x8*>(qrow + 8 * g);
    const bf16x8 qhi = *reinterpret_cast<const bf16x8*>(qrow + 32 + 8 * g);
    const int dparts = dlt[c];
    const int dh = dparts >> 4, dw = dparts & 15;

    f32x4 oacc[4];
#pragma unroll
    for (int j = 0; j < 4; j++) oacc[j] = (f32x4)0.0f;
    float ssum = 0.0f;

    const float SC = 0.022542110f;   // log2(e)/64

#pragma unroll 1
    for (int s = 0; s < 6; ++s) {
        // ---- stage V^T chunk: slots [32s, 32s+32) -> Vt[head][ch][slot'] ----
        {
            const int npair = l >> 2;
            const int chq   = l & 3;
#pragma unroll
            for (int rr = 0; rr < 2; ++rr) {
                const int ch8 = 8 * chq + 32 * rr;
                const int2 rp = *reinterpret_cast<const int2*>(&rowoff[s * 32 + 2 * npair]);
                const ushort4* pa = reinterpret_cast<const ushort4*>(qkv + rp.x + 1024 + head * HDIM + ch8);
                const ushort4* pb = reinterpret_cast<const ushort4*>(qkv + rp.y + 1024 + head * HDIM + ch8);
                ushort4 va0 = pa[0], va1 = pa[1];
                ushort4 vb0 = pb[0], vb1 = pb[1];
                const u16* va = reinterpret_cast<const u16*>(&va0);
                const u16* vb = reinterpret_cast<const u16*>(&vb0);
#pragma unroll
                for (int e = 0; e < 4; ++e) {
                    unsigned dwo = (unsigned)va[e] | ((unsigned)vb[e] << 16);
                    *reinterpret_cast<unsigned*>(&Vt[head][ch8 + e][2 * npair]) = dwo;
                }
                const u16* va2 = reinterpret_cast<const u16*>(&va1);
                const u16* vb2 = reinterpret_cast<const u16*>(&vb1);
#pragma unroll
                for (int e = 0; e < 4; ++e) {
                    unsigned dwo = (unsigned)va2[e] | ((unsigned)vb2[e] << 16);
                    *reinterpret_cast<unsigned*>(&Vt[head][ch8 + 4 + e][2 * npair]) = dwo;
                }
            }
        }

        // ---- QK^T for 2 x 16-slot blocks + mask + exp2; P stays in regs ----
        unsigned pA, pB, pC, pD;
#pragma unroll
        for (int t = 0; t < 2; ++t) {
            const int sb0 = s * 32 + t * 16;
            const int ro  = rowoff[sb0 + c];
            const u16* kr = qkv + ro + 512 + head * HDIM;
            const bf16x8 klo = *reinterpret_cast<const bf16x8*>(kr + 8 * g);
            const bf16x8 khi = *reinterpret_cast<const bf16x8*>(kr + 32 + 8 * g);
            f32x4 sf = (f32x4)0.0f;
            sf = __builtin_amdgcn_mfma_f32_16x16x32_bf16(klo, qlo, sf, 0, 0, 0);
            sf = __builtin_amdgcn_mfma_f32_16x16x32_bf16(khi, qhi, sf, 0, 0, 0);
            const int sb  = sb0 + 4 * g;
            const int wu0 = sb & 7;
            const int hh_ = (sb >> 3) & 7;
            const bool hv = ((unsigned)(hh_ - dh) < 5u);
            float e0, e1, e2, e3;
            e0 = (hv && (unsigned)(wu0 + 0 - dw) < 5u) ? exp2f(sf[0] * SC) : 0.0f;
            e1 = (hv && (unsigned)(wu0 + 1 - dw) < 5u) ? exp2f(sf[1] * SC) : 0.0f;
            e2 = (hv && (unsigned)(wu0 + 2 - dw) < 5u) ? exp2f(sf[2] * SC) : 0.0f;
            e3 = (hv && (unsigned)(wu0 + 3 - dw) < 5u) ? exp2f(sf[3] * SC) : 0.0f;
            ssum += e0 + e1 + e2 + e3;
            const unsigned p01 = (unsigned)f2b(e0) | ((unsigned)f2b(e1) << 16);
            const unsigned p23 = (unsigned)f2b(e2) | ((unsigned)f2b(e3) << 16);
            if (t == 0) { pA = p01; pB = p23; }
            else        { pC = p01; pD = p23; }
        }

        // ---- register transpose across the 4 lanes {c,c+16,c+32,c+48} ----
        asm volatile("v_permlane32_swap_b32 %0, %1" : "+v"(pA), "+v"(pC));
        asm volatile("v_permlane32_swap_b32 %0, %1" : "+v"(pB), "+v"(pD));
        asm volatile("v_permlane16_swap_b32 %0, %1" : "+v"(pA), "+v"(pC));
        asm volatile("v_permlane16_swap_b32 %0, %1" : "+v"(pB), "+v"(pD));

        // ---- PV: O[pos][ch] += P[pos][slot'] * V[slot'][ch] ----
        {
            const int4 pv = make_int4((int)pA, (int)pB, (int)pC, (int)pD);
            const bf16x8 pfrag = __builtin_bit_cast(bf16x8, pv);
#pragma unroll
            for (int j = 0; j < 4; ++j) {
                const uint2 v01 = *reinterpret_cast<const uint2*>(&Vt[head][16 * j + c][8 * g]);
                const uint2 v23 = *reinterpret_cast<const uint2*>(&Vt[head][16 * j + c][8 * g + 4]);
                const int4 vv = make_int4((int)v01.x, (int)v01.y, (int)v23.x, (int)v23.y);
                const bf16x8 vfrag = __builtin_bit_cast(bf16x8, vv);
                oacc[j] = __builtin_amdgcn_mfma_f32_16x16x32_bf16(pfrag, vfrag, oacc[j], 0, 0, 0);
            }
        }
    }

    ssum += __shfl_xor(ssum, 16);
    ssum += __shfl_xor(ssum, 32);
    if (l < 16) ssum_lds[head][c] = ssum;
    const f32x4 sums4 = *reinterpret_cast<const f32x4*>(&ssum_lds[head][4 * g]);

    const int orow = pd * (HHH * WWW) + (h0 + g) * WWW + w0;
#pragma unroll
    for (int r = 0; r < 4; ++r) {
        const float inv = 1.0f / sums4[r];
        u16* base = attnc + (size_t)(orow + r) * 512 + head * HDIM;
#pragma unroll
        for (int j = 0; j < 4; ++j)
            base[16 * j + c] = f2b(oacc[j][r] * inv);
    }
}

// ---------------------------------------------------------------------------
extern "C" void kernel_launch(void* const* d_in, const int* in_sizes, int n_in,
                              void* d_out, int out_size, void* d_ws, size_t ws_size,
                              hipStream_t stream)
{
    const float* x      = (const float*)d_in[0];
    const float* w_qkv  = (const float*)d_in[1];
    const float* b_qkv  = (const float*)d_in[2];
    const float* w_proj = (const float*)d_in[3];
    const float* b_proj = (const float*)d_in[4];
    float* out = (float*)d_out;

    u16* qkvb   = (u16*)d_ws;                         // [27648][1536]
    u16* attnc  = qkvb  + (size_t)NPOS * 1536;        // [27648][512] bf16
    u16* xb     = attnc + (size_t)NPOS * 512;         // [27648][512]
    u16* wqkvT  = xb    + (size_t)NPOS * 512;         // [1536][512]
    u16* wprojT = wqkvT + (size_t)1536 * 512;         // [512][512]

    cvt_x_bf16<<<(NPOS * 512 / 4) / 256, 256, 0, stream>>>(x, xb, NPOS * 512 / 4);
    cvt_wqkvT<<<(1536 * 512) / 256, 256, 0, stream>>>(w_qkv, wqkvT);
    cvt_wprojT<<<(512 * 512) / 256, 256, 0, stream>>>(w_proj, wprojT);

    // 1) qkv = x @ w_qkv + b_qkv  (bf16, K=512); grid 2592 = 8*324, nx=12
    gemm_bf16_mfma<<<(1536 / 128) * (NPOS / 128), 256, 0, stream>>>(
        xb, 512, wqkvT, 512, b_qkv, 512, qkvb, 1536, 1, 1536 / 128);

    // 2) attention -> bf16 [NPOS][512]
    na3d_mfma<<<NPOS / 16, 512, 0, stream>>>(qkvb, attnc);

    // 3) out = attn @ w_proj + b_proj  (bf16, K=512); grid 864 = 8*108, nx=4
    gemm_bf16_mfma<<<(512 / 128) * (NPOS / 128), 256, 0, stream>>>(
        attnc, 512, wprojT, 512, b_proj, 512, out, 512, 0, 512 / 128);
}

// Round 17
// 162.836 us; speedup vs baseline: 1.1506x; 1.1056x over previous
//
#include <hip/hip_runtime.h>

#define DIMC   512
#define NHEADS 8
#define HDIM   64
#define DD     6
#define HHH    48
#define WWW    96
#define NPOS   (DD * HHH * WWW)   // 27648

typedef unsigned short u16;
typedef __attribute__((ext_vector_type(8))) short bf16x8;
typedef __attribute__((ext_vector_type(4))) float f32x4;

static __device__ __forceinline__ float b2f(u16 u) {
    return __builtin_bit_cast(float, (unsigned)u << 16);
}
static __device__ __forceinline__ u16 f2b(float f) {
    unsigned x = __builtin_bit_cast(unsigned, f);
    return (u16)((x + 0x7fffu + ((x >> 16) & 1u)) >> 16);
}

static __device__ __forceinline__ void gload_lds16(const void* g, void* l) {
    __builtin_amdgcn_global_load_lds((const __attribute__((address_space(1))) void*)g,
                                     (__attribute__((address_space(3))) void*)l, 16, 0, 0);
}

// ---------------------------------------------------------------------------
// fused converts: one launch, block-range dispatch.
//   blocks [0, 13824)        : x f32 -> xb bf16 (float4/thread)
//   blocks [13824, 16896)    : w_qkv [512][1536] -> wqkvT [1536][512] bf16
//   blocks [16896, 17920)    : w_proj [512][512] -> wprojT [512][512] bf16
// ---------------------------------------------------------------------------
__global__ __launch_bounds__(256) void cvt_all(
    const float* __restrict__ x, const float* __restrict__ w_qkv,
    const float* __restrict__ w_proj, u16* __restrict__ xb,
    u16* __restrict__ wqkvT, u16* __restrict__ wprojT)
{
    const int bid = blockIdx.x;
    const int tid = threadIdx.x;
    if (bid < 13824) {
        const int i = bid * 256 + tid;
        float4 v = reinterpret_cast<const float4*>(x)[i];
        ushort4 o = { f2b(v.x), f2b(v.y), f2b(v.z), f2b(v.w) };
        reinterpret_cast<ushort4*>(xb)[i] = o;
    } else if (bid < 13824 + 3072) {
        const int id = (bid - 13824) * 256 + tid;
        const int nn = id >> 9, kk = id & 511;
        wqkvT[id] = f2b(w_qkv[(size_t)kk * 1536 + nn]);
    } else {
        const int id = (bid - 16896) * 256 + tid;
        const int nn = id >> 9, kk = id & 511;
        wprojT[id] = f2b(w_proj[(size_t)kk * 512 + nn]);
    }
}

// ---------------------------------------------------------------------------
// bf16 MFMA GEMM — R17: 256x128 tile, BK=64, 8 waves (4M x 2N), 2-phase.
// Same verified schedule/swizzle/k-order as R13 (bit-identical math); only
// the block tile doubled in M: block count halves -> per-step barrier-drain
// events halve while per-step work doubles. LDS 48 KB -> 3 blocks/CU.
// Staging (dest = wave base + lane*16, rule 21): A 4 issues/wave rows
// w*32+(l>>3)+8q; B 2 issues rows w*16+(l>>3)+8q; phys chunk l&7 holds
// source col chunk (l&7)^(row&7), row&7 == l>>3. Frag read chunk
// (4h+g)^(c&7) per-lane constant (row&7 == c&7). Measured 0 conflicts (R8+).
// ---------------------------------------------------------------------------
__global__ __launch_bounds__(512) void gemm_bf16_mfma(
    const u16* __restrict__ A, int lda,
    const u16* __restrict__ B, int ldb,
    const float* __restrict__ bias, int Kp,
    void* __restrict__ Cout, int ldc, int cmode, int nx)
{
    __shared__ u16 As[256 * 64];
    __shared__ u16 Bs[128 * 64];

    const int tid = threadIdx.x;
    const int l   = tid & 63;
    const int w   = tid >> 6;
    const int wr  = w >> 1;        // 0..3 (M)
    const int wc  = w & 1;         // 0..1 (N)

    // XCD swizzle: gridDim.x % 8 == 0 guaranteed by launch shapes
    const int cpx = gridDim.x >> 3;
    const int idp = (blockIdx.x & 7) * cpx + (blockIdx.x >> 3);
    const int by  = idp / nx;
    const int bx  = idp - by * nx;
    const int m0  = by * 256;
    const int n0  = bx * 128;

    const int lrow = l >> 3;                       // 0..7
    const int swz  = ((l & 7) ^ lrow) * 8;         // source col elems (swizzled)
    const int arow = w * 32 + lrow;
    const int brow = w * 16 + lrow;

    const u16* ga = A + (size_t)(m0 + arow) * lda + swz;
    const u16* gb = B + (size_t)(n0 + brow) * ldb + swz;
    const size_t a8 = (size_t)8 * lda;
    const size_t b8 = (size_t)8 * ldb;
    u16* const la0 = As + w * 2048;                // wave-uniform LDS bases
    u16* const lb0 = Bs + w * 1024;

    f32x4 acc[4][4];
#pragma unroll
    for (int i = 0; i < 4; i++)
#pragma unroll
        for (int j = 0; j < 4; j++) acc[i][j] = (f32x4)0.0f;

    const int c   = l & 15;
    const int g   = l >> 4;
    const int lk0 = ((0 * 4 + g) ^ (c & 7)) * 8;
    const int lk1 = ((1 * 4 + g) ^ (c & 7)) * 8;

#pragma unroll 1
    for (int k0 = 0; k0 < Kp; k0 += 64) {
#pragma unroll
        for (int q = 0; q < 4; ++q)
            gload_lds16(ga + q * a8, la0 + q * 512);
#pragma unroll
        for (int q = 0; q < 2; ++q)
            gload_lds16(gb + q * b8, lb0 + q * 512);
        ga += 64; gb += 64;
        __syncthreads();

        {
            bf16x8 af[4], bfr[4];
#pragma unroll
            for (int f = 0; f < 4; f++) {
                af[f]  = *reinterpret_cast<const bf16x8*>(&As[(wr * 64 + f * 16 + c) * 64 + lk0]);
                bfr[f] = *reinterpret_cast<const bf16x8*>(&Bs[(wc * 64 + f * 16 + c) * 64 + lk0]);
            }
#pragma unroll
            for (int i = 0; i < 4; i++)
#pragma unroll
                for (int j = 0; j < 4; j++)
                    acc[i][j] = __builtin_amdgcn_mfma_f32_16x16x32_bf16(af[i], bfr[j], acc[i][j], 0, 0, 0);
        }
        {
            bf16x8 af[4], bfr[4];
#pragma unroll
            for (int f = 0; f < 4; f++) {
                af[f]  = *reinterpret_cast<const bf16x8*>(&As[(wr * 64 + f * 16 + c) * 64 + lk1]);
                bfr[f] = *reinterpret_cast<const bf16x8*>(&Bs[(wc * 64 + f * 16 + c) * 64 + lk1]);
            }
#pragma unroll
            for (int i = 0; i < 4; i++)
#pragma unroll
                for (int j = 0; j < 4; j++)
                    acc[i][j] = __builtin_amdgcn_mfma_f32_16x16x32_bf16(af[i], bfr[j], acc[i][j], 0, 0, 0);
        }
        __syncthreads();
    }

#pragma unroll
    for (int i = 0; i < 4; i++) {
        const int mb = m0 + wr * 64 + i * 16 + g * 4;
#pragma unroll
        for (int j = 0; j < 4; j++) {
            const int n = n0 + wc * 64 + j * 16 + c;
            const float bv = bias[n];
#pragma unroll
            for (int r = 0; r < 4; r++) {
                const float v = acc[i][j][r] + bv;
                if (cmode) reinterpret_cast<u16*>(Cout)[(size_t)(mb + r) * ldc + n] = f2b(v);
                else       reinterpret_cast<float*>(Cout)[(size_t)(mb + r) * ldc + n] = v;
            }
        }
    }
}

// ---------------------------------------------------------------------------
// MFMA neighborhood attention, 1x4x4 tiles — R16 configuration (known-good):
// permlane register transpose, no Pbuf.
// ---------------------------------------------------------------------------
__global__ __launch_bounds__(512, 4) void na3d_mfma(
    const u16* __restrict__ qkv, u16* __restrict__ attnc)
{
    __shared__ int   rowoff[192];
    __shared__ int   dlt[16];
    __shared__ u16   Vt[NHEADS][64][36];
    __shared__ float ssum_lds[NHEADS][16];

    const int bid  = blockIdx.x;
    const int tile = (bid & 7) * 216 + (bid >> 3);
    const int pd  = tile / 288;
    const int rem = tile - pd * 288;
    const int h0  = (rem / 24) * 4;
    const int w0  = (rem % 24) * 4;
    const int sd  = min(max(pd - 1, 0), DD - 3);
    const int shb = min(max(h0 - 2, 0), HHH - 5);
    const int swb = min(max(w0 - 2, 0), WWW - 5);

    const int tid = threadIdx.x;
    if (tid < 192) {
        const int dd = tid >> 6, hh = (tid >> 3) & 7, wu = tid & 7;
        const int row = (sd + dd) * (HHH * WWW)
                      + min(shb + hh, HHH - 1) * WWW + min(swb + wu, WWW - 1);
        rowoff[tid] = row * 1536;
    }
    if (tid < 16) {
        const int ph = h0 + (tid >> 2), pw = w0 + (tid & 3);
        const int dh = min(max(ph - 2, 0), HHH - 5) - shb;
        const int dw = min(max(pw - 2, 0), WWW - 5) - swb;
        dlt[tid] = (dh << 4) | dw;
    }
    __syncthreads();

    const int head = tid >> 6;
    const int l    = tid & 63;
    const int g    = l >> 4;
    const int c    = l & 15;

    const int qrowi = pd * (HHH * WWW) + (h0 + (c >> 2)) * WWW + (w0 + (c & 3));
    const u16* qrow = qkv + (size_t)qrowi * 1536 + head * HDIM;
    const bf16x8 qlo = *reinterpret_cast<const bf16x8*>(qrow + 8 * g);
    const bf16x8 qhi = *reinterpret_cast<const bf16x8*>(qrow + 32 + 8 * g);
    const int dparts = dlt[c];
    const int dh = dparts >> 4, dw = dparts & 15;

    f32x4 oacc[4];
#pragma unroll
    for (int j = 0; j < 4; j++) oacc[j] = (f32x4)0.0f;
    float ssum = 0.0f;

    const float SC = 0.022542110f;   // log2(e)/64

#pragma unroll 1
    for (int s = 0; s < 6; ++s) {
        // ---- stage V^T chunk: slots [32s, 32s+32) -> Vt[head][ch][slot'] ----
        {
            const int npair = l >> 2;
            const int chq   = l & 3;
#pragma unroll
            for (int rr = 0; rr < 2; ++rr) {
                const int ch8 = 8 * chq + 32 * rr;
                const int2 rp = *reinterpret_cast<const int2*>(&rowoff[s * 32 + 2 * npair]);
                const ushort4* pa = reinterpret_cast<const ushort4*>(qkv + rp.x + 1024 + head * HDIM + ch8);
                const ushort4* pb = reinterpret_cast<const ushort4*>(qkv + rp.y + 1024 + head * HDIM + ch8);
                ushort4 va0 = pa[0], va1 = pa[1];
                ushort4 vb0 = pb[0], vb1 = pb[1];
                const u16* va = reinterpret_cast<const u16*>(&va0);
                const u16* vb = reinterpret_cast<const u16*>(&vb0);
#pragma unroll
                for (int e = 0; e < 4; ++e) {
                    unsigned dwo = (unsigned)va[e] | ((unsigned)vb[e] << 16);
                    *reinterpret_cast<unsigned*>(&Vt[head][ch8 + e][2 * npair]) = dwo;
                }
                const u16* va2 = reinterpret_cast<const u16*>(&va1);
                const u16* vb2 = reinterpret_cast<const u16*>(&vb1);
#pragma unroll
                for (int e = 0; e < 4; ++e) {
                    unsigned dwo = (unsigned)va2[e] | ((unsigned)vb2[e] << 16);
                    *reinterpret_cast<unsigned*>(&Vt[head][ch8 + 4 + e][2 * npair]) = dwo;
                }
            }
        }

        // ---- QK^T for 2 x 16-slot blocks + mask + exp2; P stays in regs ----
        unsigned pA, pB, pC, pD;
#pragma unroll
        for (int t = 0; t < 2; ++t) {
            const int sb0 = s * 32 + t * 16;
            const int ro  = rowoff[sb0 + c];
            const u16* kr = qkv + ro + 512 + head * HDIM;
            const bf16x8 klo = *reinterpret_cast<const bf16x8*>(kr + 8 * g);
            const bf16x8 khi = *reinterpret_cast<const bf16x8*>(kr + 32 + 8 * g);
            f32x4 sf = (f32x4)0.0f;
            sf = __builtin_amdgcn_mfma_f32_16x16x32_bf16(klo, qlo, sf, 0, 0, 0);
            sf = __builtin_amdgcn_mfma_f32_16x16x32_bf16(khi, qhi, sf, 0, 0, 0);
            const int sb  = sb0 + 4 * g;
            const int wu0 = sb & 7;
            const int hh_ = (sb >> 3) & 7;
            const bool hv = ((unsigned)(hh_ - dh) < 5u);
            float e0, e1, e2, e3;
            e0 = (hv && (unsigned)(wu0 + 0 - dw) < 5u) ? exp2f(sf[0] * SC) : 0.0f;
            e1 = (hv && (unsigned)(wu0 + 1 - dw) < 5u) ? exp2f(sf[1] * SC) : 0.0f;
            e2 = (hv && (unsigned)(wu0 + 2 - dw) < 5u) ? exp2f(sf[2] * SC) : 0.0f;
            e3 = (hv && (unsigned)(wu0 + 3 - dw) < 5u) ? exp2f(sf[3] * SC) : 0.0f;
            ssum += e0 + e1 + e2 + e3;
            const unsigned p01 = (unsigned)f2b(e0) | ((unsigned)f2b(e1) << 16);
            const unsigned p23 = (unsigned)f2b(e2) | ((unsigned)f2b(e3) << 16);
            if (t == 0) { pA = p01; pB = p23; }
            else        { pC = p01; pD = p23; }
        }

        // ---- register transpose across the 4 lanes {c,c+16,c+32,c+48} ----
        asm volatile("v_permlane32_swap_b32 %0, %1" : "+v"(pA), "+v"(pC));
        asm volatile("v_permlane32_swap_b32 %0, %1" : "+v"(pB), "+v"(pD));
        asm volatile("v_permlane16_swap_b32 %0, %1" : "+v"(pA), "+v"(pC));
        asm volatile("v_permlane16_swap_b32 %0, %1" : "+v"(pB), "+v"(pD));

        // ---- PV: O[pos][ch] += P[pos][slot'] * V[slot'][ch] ----
        {
            const int4 pv = make_int4((int)pA, (int)pB, (int)pC, (int)pD);
            const bf16x8 pfrag = __builtin_bit_cast(bf16x8, pv);
#pragma unroll
            for (int j = 0; j < 4; ++j) {
                const uint2 v01 = *reinterpret_cast<const uint2*>(&Vt[head][16 * j + c][8 * g]);
                const uint2 v23 = *reinterpret_cast<const uint2*>(&Vt[head][16 * j + c][8 * g + 4]);
                const int4 vv = make_int4((int)v01.x, (int)v01.y, (int)v23.x, (int)v23.y);
                const bf16x8 vfrag = __builtin_bit_cast(bf16x8, vv);
                oacc[j] = __builtin_amdgcn_mfma_f32_16x16x32_bf16(pfrag, vfrag, oacc[j], 0, 0, 0);
            }
        }
    }

    ssum += __shfl_xor(ssum, 16);
    ssum += __shfl_xor(ssum, 32);
    if (l < 16) ssum_lds[head][c] = ssum;
    const f32x4 sums4 = *reinterpret_cast<const f32x4*>(&ssum_lds[head][4 * g]);

    const int orow = pd * (HHH * WWW) + (h0 + g) * WWW + w0;
#pragma unroll
    for (int r = 0; r < 4; ++r) {
        const float inv = 1.0f / sums4[r];
        u16* base = attnc + (size_t)(orow + r) * 512 + head * HDIM;
#pragma unroll
        for (int j = 0; j < 4; ++j)
            base[16 * j + c] = f2b(oacc[j][r] * inv);
    }
}

// ---------------------------------------------------------------------------
extern "C" void kernel_launch(void* const* d_in, const int* in_sizes, int n_in,
                              void* d_out, int out_size, void* d_ws, size_t ws_size,
                              hipStream_t stream)
{
    const float* x      = (const float*)d_in[0];
    const float* w_qkv  = (const float*)d_in[1];
    const float* b_qkv  = (const float*)d_in[2];
    const float* w_proj = (const float*)d_in[3];
    const float* b_proj = (const float*)d_in[4];
    float* out = (float*)d_out;

    u16* qkvb   = (u16*)d_ws;                         // [27648][1536]
    u16* attnc  = qkvb  + (size_t)NPOS * 1536;        // [27648][512] bf16
    u16* xb     = attnc + (size_t)NPOS * 512;         // [27648][512]
    u16* wqkvT  = xb    + (size_t)NPOS * 512;         // [1536][512]
    u16* wprojT = wqkvT + (size_t)1536 * 512;         // [512][512]

    // 0) all converts in one launch (13824 + 3072 + 1024 blocks)
    cvt_all<<<17920, 256, 0, stream>>>(x, w_qkv, w_proj, xb, wqkvT, wprojT);

    // 1) qkv = x @ w_qkv + b_qkv ; grid (27648/256)*(1536/128) = 1296 = 8*162
    gemm_bf16_mfma<<<(NPOS / 256) * (1536 / 128), 512, 0, stream>>>(
        xb, 512, wqkvT, 512, b_qkv, 512, qkvb, 1536, 1, 1536 / 128);

    // 2) attention -> bf16 [NPOS][512]
    na3d_mfma<<<NPOS / 16, 512, 0, stream>>>(qkvb, attnc);

    // 3) out = attn @ w_proj + b_proj ; grid 108*4 = 432 = 8*54
    gemm_bf16_mfma<<<(NPOS / 256) * (512 / 128), 512, 0, stream>>>(
        attnc, 512, wprojT, 512, b_proj, 512, out, 512, 0, 512 / 128);
}